// Round 7
// baseline (141.598 us; speedup 1.0000x reference)
//
#include <hip/hip_runtime.h>

#define CC 512
#define TT 4096
#define NB 4
#define NH 8
#define HD 64

typedef __attribute__((ext_vector_type(8))) short s16x8;
typedef __attribute__((ext_vector_type(4))) float f32x4;
typedef __attribute__((ext_vector_type(4))) unsigned int u32x4;
typedef __attribute__((ext_vector_type(2))) unsigned int u32x2;

// float -> bf16 bits, round-to-nearest-even
__device__ __forceinline__ short f2bf(float f) {
    unsigned u = __float_as_uint(f);
    unsigned r = (u + 0x7fffu + ((u >> 16) & 1u)) >> 16;
    return (short)r;
}
__device__ __forceinline__ unsigned pkbf(float a, float b) {
    return (unsigned)(unsigned short)f2bf(a) | ((unsigned)(unsigned short)f2bf(b) << 16);
}

__device__ __forceinline__ void gld_lds16(const void* g, void* s) {
    __builtin_amdgcn_global_load_lds(
        (const __attribute__((address_space(1))) unsigned int*)g,
        (__attribute__((address_space(3))) unsigned int*)s, 16, 0, 0);
}

// ---------------- weight fp32 -> bf16 (4 matrices concatenated) ----------------
__global__ __launch_bounds__(256) void cvt_w_k(const float* __restrict__ w0,
                                               const float* __restrict__ w1,
                                               const float* __restrict__ w2,
                                               const float* __restrict__ w3,
                                               short* __restrict__ dst) {
    int i = blockIdx.x * 256 + threadIdx.x;  // 4*262144 total
    const float* s = (i < 262144) ? w0 : (i < 524288) ? w1 : (i < 786432) ? w2 : w3;
    dst[i] = f2bf(s[i & 262143]);
}

// ---------- transpose+convert: fp32 (B,C,T) -> bf16 (B,T,C), x and cond -------
__global__ __launch_bounds__(256) void trans_k(const float* __restrict__ x,
                                               const float* __restrict__ cond,
                                               short* __restrict__ xT,
                                               short* __restrict__ condT) {
    __shared__ float tile[64][65];
    int z = blockIdx.z;          // 0..7
    int b = z & 3;
    const float* src = (z < 4 ? x : cond) + (size_t)b * CC * TT;
    short* dst = (z < 4 ? xT : condT) + (size_t)b * TT * CC;
    int tx = threadIdx.x & 63, ty = threadIdx.x >> 6;
    int t0 = blockIdx.x * 64, c0 = blockIdx.y * 64;
#pragma unroll
    for (int r = 0; r < 64; r += 4)
        tile[ty + r][tx] = src[(size_t)(c0 + ty + r) * TT + t0 + tx];
    __syncthreads();
#pragma unroll
    for (int r = 0; r < 64; r += 4)
        dst[(size_t)(t0 + ty + r) * CC + c0 + tx] = f2bf(tile[tx][ty + r]);
}

// ---------------- 256x128x64 GEMM core, A(weights) from L2, B LDS-dbuf --------
// Wm: [512][512] bf16 (o,k) row-major. Sm: [4096][512] bf16 (t,k) row-major.
// Block = 256 threads, 4 waves (2 o-panels x 2 t-panels), wave tile 128o x 64t.
// A fragments read directly from global (W is 512KB, L2-resident).
// B tile 128t x 64k staged to LDS, double-buffered, prefetched.
// OMODE=0: Df[o][t] fp32 = W*S^T + bias.
// OMODE=1: Db[t][o] bf16 (swapped MFMA operands).
// OMODE=2: Db[o][t] bf16.
template <int OMODE>
__device__ __forceinline__ void gemm256(const short* __restrict__ Wm,
                                        const short* __restrict__ Sm,
                                        const float* __restrict__ bias,
                                        float* __restrict__ Df,
                                        short* __restrict__ Db) {
    __shared__ short Bl[2][128 * 64] __attribute__((aligned(16)));
    const int tid = threadIdx.x;
    const int lane = tid & 63;
    const int wid = tid >> 6;
    const int o0 = blockIdx.y * 256;
    const int t0 = blockIdx.x * 128;
    const int wm = (wid >> 1) * 128;   // o-panel
    const int wn = (wid & 1) * 64;     // t-panel

    f32x4 acc[8][4];
#pragma unroll
    for (int i = 0; i < 8; i++)
#pragma unroll
        for (int j = 0; j < 4; j++) acc[i][j] = (f32x4){0.f, 0.f, 0.f, 0.f};

    // ---- stage B k-tile into LDS buffer (1024 16B chunks, 4 per thread) ----
    // slot s of row holds global chunk c = s ^ (row&7)  (XOR swizzle)
#define STAGE_B(BUF, K0)                                                     \
    {                                                                        \
        _Pragma("unroll") for (int it = 0; it < 4; ++it) {                   \
            int idx = it * 256 + tid;                                        \
            int row = idx >> 3, sl = idx & 7;                                \
            int c = sl ^ (row & 7);                                          \
            gld_lds16(Sm + (size_t)(t0 + row) * CC + (K0) + c * 8,           \
                      &Bl[BUF][idx * 8]);                                    \
        }                                                                    \
    }

    STAGE_B(0, 0);
    __syncthreads();  // prologue tile visible

    for (int kt = 0; kt < 8; ++kt) {
        const int k0 = kt * 64;
        const int buf = kt & 1;

        // A fragments from global (issued BEFORE the prefetch stage so the
        // compiler's in-order vmcnt wait on af does not drain the stage)
        s16x8 af[2][8];
        const short* abase =
            Wm + (size_t)(o0 + wm + (lane & 15)) * CC + k0 + (lane >> 4) * 8;
#pragma unroll
        for (int ai = 0; ai < 8; ++ai) {
            af[0][ai] = *(const s16x8*)(abase + (size_t)ai * 16 * CC);
            af[1][ai] = *(const s16x8*)(abase + (size_t)ai * 16 * CC + 32);
        }

        if (kt < 7) STAGE_B(buf ^ 1, k0 + 64);  // prefetch next k-tile

#pragma unroll
        for (int kk = 0; kk < 2; ++kk) {
            s16x8 bfr[4];
#pragma unroll
            for (int bi = 0; bi < 4; ++bi) {
                int n = wn + bi * 16 + (lane & 15);
                bfr[bi] = *(const s16x8*)&Bl[buf][(n * 64 + kk * 32 +
                                                   (lane >> 4) * 8) ^
                                                  ((n & 7) << 3)];
            }
#pragma unroll
            for (int ai = 0; ai < 8; ++ai)
#pragma unroll
                for (int bi = 0; bi < 4; ++bi) {
                    if (OMODE == 1)  // D rows = t (bfr), cols = o (af)
                        acc[ai][bi] = __builtin_amdgcn_mfma_f32_16x16x32_bf16(
                            bfr[bi], af[kk][ai], acc[ai][bi], 0, 0, 0);
                    else
                        acc[ai][bi] = __builtin_amdgcn_mfma_f32_16x16x32_bf16(
                            af[kk][ai], bfr[bi], acc[ai][bi], 0, 0, 0);
                }
        }
        __syncthreads();  // drains vmcnt(0): prefetched tile visible, buf free
    }
#undef STAGE_B

    const int col = lane & 15;
    const int rg = (lane >> 4) << 2;
    if (OMODE == 1) {
#pragma unroll
        for (int ai = 0; ai < 8; ++ai) {
            int o = o0 + wm + ai * 16 + col;
            float bv = bias[o];
#pragma unroll
            for (int bi = 0; bi < 4; ++bi) {
                int t = t0 + wn + bi * 16 + rg;
                f32x4 a = acc[ai][bi];
#pragma unroll
                for (int r = 0; r < 4; r++)
                    Db[(size_t)(t + r) * CC + o] = f2bf(a[r] + bv);
            }
        }
    } else {
#pragma unroll
        for (int ai = 0; ai < 8; ++ai) {
            int o = o0 + wm + ai * 16 + rg;
#pragma unroll
            for (int bi = 0; bi < 4; ++bi) {
                int t = t0 + wn + bi * 16 + col;
                f32x4 a = acc[ai][bi];
#pragma unroll
                for (int r = 0; r < 4; r++) {
                    if (OMODE == 0)
                        Df[(size_t)(o + r) * TT + t] = a[r] + bias[o + r];
                    else
                        Db[(size_t)(o + r) * TT + t] = f2bf(a[r] + bias[o + r]);
                }
            }
        }
    }
}

// QKV: Q,K -> bf16 [b][t][C]; V -> bf16 [b][c][t]
__global__ __launch_bounds__(256, 2) void gemm_qkv_k(
    const short* __restrict__ Wb, const short* __restrict__ xT,
    const short* __restrict__ condT, const float* __restrict__ bq,
    const float* __restrict__ bk, const float* __restrict__ bv,
    short* __restrict__ qkvT) {
    int z = blockIdx.z, which = z >> 2, b = z & 3;
    const short* Wm = Wb + (size_t)which * CC * CC;
    const short* Sm = (which == 0 ? xT : condT) + (size_t)b * TT * CC;
    short* Db = qkvT + ((size_t)which * NB + b) * TT * CC;
    if (which == 2)
        gemm256<2>(Wm, Sm, bv, nullptr, Db);
    else
        gemm256<1>(Wm, Sm, which == 0 ? bq : bk, nullptr, Db);
}

__global__ __launch_bounds__(256, 2) void gemm_o_k(const short* __restrict__ Wb,
                                                   const short* __restrict__ outT,
                                                   const float* __restrict__ bo,
                                                   float* __restrict__ out) {
    int b = blockIdx.z;
    gemm256<0>(Wb + 3 * (size_t)CC * CC, outT + (size_t)b * TT * CC, bo,
               out + (size_t)b * CC * TT, nullptr);
}

// ---------------- windowed attention v6: MFMA-based ----------------
// Q,K bf16 [b][t][C]; V bf16 [b][c][t]; out bf16 [b][t][C].
// Block = 1 wave = 32 t-rows of one (b,h). Per 16-t block m:
//  S^T(32s x 16t) = mfma(K_rows, Q_rows) x4; softmax in C/D layout
//  (cols = t are lane-resident; reduce over s = regs + shfl_xor 16/32);
//  P bounced via LDS [t][s] (b64 writes -> b128 row-frag reads);
//  out^T(64d x 16t) = mfma(VT_rows, P_rows) x4.
__global__ __launch_bounds__(64, 4) void attn6_k(const short* __restrict__ qkvT,
                                                 short* __restrict__ outT) {
    __shared__ unsigned P_lds[2][16][18];  // [dbuf][t][s-dwords], 72B row stride
    const int lane = threadIdx.x;
    const int g = lane >> 4, tp = lane & 15;
    const int T0 = blockIdx.x * 32;
    const int h = blockIdx.y, b = blockIdx.z;
    const size_t BTC = (size_t)NB * TT * CC;
    const short* qg = qkvT + (size_t)b * TT * CC + h * HD;
    const short* kg = qg + BTC;
    const short* vg = qkvT + 2 * BTC + (size_t)b * TT * CC + (size_t)(h * HD) * TT;
    const f32x4 z4 = {0.f, 0.f, 0.f, 0.f};

    // K fragment for key-block base T0-8 (shared j=0 of m=0)
    s16x8 ka0, ka1;
    {
        int s = T0 - 8 + tp;
        s = s < 0 ? 0 : s;
        const short* p = &kg[(size_t)s * CC + g * 8];
        ka0 = *(const s16x8*)p;
        ka1 = *(const s16x8*)(p + 32);
    }

#pragma unroll
    for (int m = 0; m < 2; ++m) {
        const int sb0 = T0 + 16 * m - 8;   // key band base for this t-block
        // j=1 key block (rows sb0+16..sb0+31)
        s16x8 kb0, kb1;
        {
            int s = sb0 + 16 + tp;
            s = s > TT - 1 ? TT - 1 : s;
            const short* p = &kg[(size_t)s * CC + g * 8];
            kb0 = *(const s16x8*)p;
            kb1 = *(const s16x8*)(p + 32);
        }
        // Q fragments (t-rows T0+16m..+15)
        s16x8 q0, q1;
        {
            const short* p = &qg[(size_t)(T0 + 16 * m + tp) * CC + g * 8];
            q0 = *(const s16x8*)p;
            q1 = *(const s16x8*)(p + 32);
        }
        // V^T fragments: row d = dblk*16+tp, cols [cb, cb+8)
        int cb = sb0 + g * 8;
        cb = cb < 0 ? 0 : (cb > TT - 8 ? TT - 8 : cb);
        const short* vrow = &vg[(size_t)tp * TT + cb];
        s16x8 vf0 = *(const s16x8*)(vrow);
        s16x8 vf1 = *(const s16x8*)(vrow + (size_t)16 * TT);
        s16x8 vf2 = *(const s16x8*)(vrow + (size_t)32 * TT);
        s16x8 vf3 = *(const s16x8*)(vrow + (size_t)48 * TT);

        // S^T = K . Q^T : D[s][t], lane holds s = 16j+4g+r, t = tp
        f32x4 s0 = __builtin_amdgcn_mfma_f32_16x16x32_bf16(ka0, q0, z4, 0, 0, 0);
        s0 = __builtin_amdgcn_mfma_f32_16x16x32_bf16(ka1, q1, s0, 0, 0, 0);
        f32x4 s1 = __builtin_amdgcn_mfma_f32_16x16x32_bf16(kb0, q0, z4, 0, 0, 0);
        s1 = __builtin_amdgcn_mfma_f32_16x16x32_bf16(kb1, q1, s1, 0, 0, 0);

        // softmax over the 16-wide window of column t=tp (of 32 s-slots)
        float lg[8];
        float mymax = -3.0e38f;
#pragma unroll
        for (int jr = 0; jr < 8; ++jr) {
            const int j = jr >> 2, r = jr & 3;
            float v = (j ? s1[r] : s0[r]) * 0.125f;
            const int sl = 16 * j + 4 * g + r;
            const int sg = sb0 + sl;
            v = ((unsigned)sg < (unsigned)TT) ? v : 0.f;  // zero-pad logit
            lg[jr] = v;
            const bool inw = (unsigned)(sl - tp) < 16u;   // s in [t-8, t+7]
            mymax = inw ? fmaxf(mymax, v) : mymax;
        }
        mymax = fmaxf(mymax, __shfl_xor(mymax, 16));
        mymax = fmaxf(mymax, __shfl_xor(mymax, 32));
        float e[8], Z = 0.f;
#pragma unroll
        for (int jr = 0; jr < 8; ++jr) {
            const int j = jr >> 2, r = jr & 3;
            const int sl = 16 * j + 4 * g + r;
            const bool inw = (unsigned)(sl - tp) < 16u;
            const float ee = inw ? __expf(lg[jr] - mymax) : 0.f;
            e[jr] = ee;
            Z += ee;
        }
        Z += __shfl_xor(Z, 16);
        Z += __shfl_xor(Z, 32);
        const float inv = 1.f / Z;
#pragma unroll
        for (int jr = 0; jr < 8; ++jr) {
            const int sg = sb0 + 16 * (jr >> 2) + 4 * g + (jr & 3);
            e[jr] = ((unsigned)sg < (unsigned)TT) ? e[jr] * inv : 0.f;  // numerator mask
        }

        // bounce P to LDS in [t][s] layout (row-frag form for PV)
        unsigned* prow = &P_lds[m & 1][tp][0];
        *(u32x2*)&prow[2 * g] = (u32x2){pkbf(e[0], e[1]), pkbf(e[2], e[3])};
        *(u32x2*)&prow[8 + 2 * g] = (u32x2){pkbf(e[4], e[5]), pkbf(e[6], e[7])};
        __syncthreads();
        const s16x8 pf = *(const s16x8*)&P_lds[m & 1][tp][4 * g];

        // out^T = V^T . P^T : D[d][t], lane holds d = 4g+r, t = tp
        f32x4 o0 = __builtin_amdgcn_mfma_f32_16x16x32_bf16(vf0, pf, z4, 0, 0, 0);
        f32x4 o1 = __builtin_amdgcn_mfma_f32_16x16x32_bf16(vf1, pf, z4, 0, 0, 0);
        f32x4 o2 = __builtin_amdgcn_mfma_f32_16x16x32_bf16(vf2, pf, z4, 0, 0, 0);
        f32x4 o3 = __builtin_amdgcn_mfma_f32_16x16x32_bf16(vf3, pf, z4, 0, 0, 0);

        short* orow = &outT[((size_t)b * TT + T0 + 16 * m + tp) * CC + h * HD + 4 * g];
        *(u32x2*)&orow[0] = (u32x2){pkbf(o0[0], o0[1]), pkbf(o0[2], o0[3])};
        *(u32x2*)&orow[16] = (u32x2){pkbf(o1[0], o1[1]), pkbf(o1[2], o1[3])};
        *(u32x2*)&orow[32] = (u32x2){pkbf(o2[0], o2[1]), pkbf(o2[2], o2[3])};
        *(u32x2*)&orow[48] = (u32x2){pkbf(o3[0], o3[1]), pkbf(o3[2], o3[3])};

        ka0 = kb0;  // j=1 block of m is j=0 block of m+1
        ka1 = kb1;
    }
}

extern "C" void kernel_launch(void* const* d_in, const int* in_sizes, int n_in,
                              void* d_out, int out_size, void* d_ws, size_t ws_size,
                              hipStream_t stream) {
    const float* x    = (const float*)d_in[0];
    const float* cond = (const float*)d_in[1];
    const float* Wq   = (const float*)d_in[2];
    const float* bq   = (const float*)d_in[3];
    const float* Wk   = (const float*)d_in[4];
    const float* bk   = (const float*)d_in[5];
    const float* Wv   = (const float*)d_in[6];
    const float* bv   = (const float*)d_in[7];
    const float* Wo   = (const float*)d_in[8];
    const float* bo   = (const float*)d_in[9];

    char* ws = (char*)d_ws;
    // layout: Wb(2MB) | xT(16MB) | condT(16MB) | qkv bf16 (48MB: Q,K [b][t][C]; V [b][c][t])
    short* Wb    = (short*)ws;
    short* xT    = (short*)(ws + (2u << 20));
    short* condT = (short*)(ws + (18u << 20));
    short* qkvT  = (short*)(ws + (34u << 20));
    short* outT  = xT;  // xT dead after Q GEMM; reuse for attention output^T

    cvt_w_k<<<4096, 256, 0, stream>>>(Wq, Wk, Wv, Wo, Wb);
    trans_k<<<dim3(TT / 64, CC / 64, 8), 256, 0, stream>>>(x, cond, xT, condT);
    gemm_qkv_k<<<dim3(TT / 128, CC / 256, 12), 256, 0, stream>>>(Wb, xT, condT, bq, bk, bv, qkvT);
    attn6_k<<<dim3(TT / 32, NH, NB), 64, 0, stream>>>(qkvT, outT);
    gemm_o_k<<<dim3(TT / 128, CC / 256, 4), 256, 0, stream>>>(Wb, outT, bo, (float*)d_out);
}

// Round 8
// 96.393 us; speedup vs baseline: 1.4690x; 1.4690x over previous
//
#include <hip/hip_runtime.h>

#define CC 512
#define TT 4096
#define NB 4
#define NH 8
#define HD 64

typedef __attribute__((ext_vector_type(8))) short s16x8;
typedef __attribute__((ext_vector_type(4))) float f32x4;
typedef __attribute__((ext_vector_type(4))) unsigned int u32x4;

#if defined(__has_builtin)
#  if __has_builtin(__builtin_amdgcn_fdot2_f32_bf16)
#    define HAS_BF16_DOT2 1
#  else
#    define HAS_BF16_DOT2 0
#  endif
#else
#  define HAS_BF16_DOT2 0
#endif

// float -> bf16 bits, round-to-nearest-even
__device__ __forceinline__ short f2bf(float f) {
    unsigned u = __float_as_uint(f);
    unsigned r = (u + 0x7fffu + ((u >> 16) & 1u)) >> 16;
    return (short)r;
}
__device__ __forceinline__ float bf2f(short s) {
    return __uint_as_float(((unsigned)(unsigned short)s) << 16);
}

#if HAS_BF16_DOT2
typedef __attribute__((ext_vector_type(2))) __bf16 bf16x2;
__device__ __forceinline__ float dot2bf(unsigned a, unsigned b, float c) {
    return __builtin_amdgcn_fdot2_f32_bf16(__builtin_bit_cast(bf16x2, a),
                                           __builtin_bit_cast(bf16x2, b), c, false);
}
#else
__device__ __forceinline__ float dot2bf(unsigned a, unsigned b, float c) {
    float r = fmaf(bf2f((short)(a & 0xffffu)), bf2f((short)(b & 0xffffu)), c);
    return fmaf(bf2f((short)(a >> 16)), bf2f((short)(b >> 16)), r);
}
#endif

__device__ __forceinline__ void gld_lds16(const void* g, void* s) {
    __builtin_amdgcn_global_load_lds(
        (const __attribute__((address_space(1))) unsigned int*)g,
        (__attribute__((address_space(3))) unsigned int*)s, 16, 0, 0);
}

// ---------------- weight fp32 -> bf16 (4 matrices concatenated) ----------------
__global__ __launch_bounds__(256) void cvt_w_k(const float* __restrict__ w0,
                                               const float* __restrict__ w1,
                                               const float* __restrict__ w2,
                                               const float* __restrict__ w3,
                                               short* __restrict__ dst) {
    int i = blockIdx.x * 256 + threadIdx.x;  // 4*262144 total
    const float* s = (i < 262144) ? w0 : (i < 524288) ? w1 : (i < 786432) ? w2 : w3;
    dst[i] = f2bf(s[i & 262143]);
}

// ---------- transpose+convert: fp32 (B,C,T) -> bf16 (B,T,C), x and cond -------
__global__ __launch_bounds__(256) void trans_k(const float* __restrict__ x,
                                               const float* __restrict__ cond,
                                               short* __restrict__ xT,
                                               short* __restrict__ condT) {
    __shared__ float tile[64][65];
    int z = blockIdx.z;          // 0..7
    int b = z & 3;
    const float* src = (z < 4 ? x : cond) + (size_t)b * CC * TT;
    short* dst = (z < 4 ? xT : condT) + (size_t)b * TT * CC;
    int tx = threadIdx.x & 63, ty = threadIdx.x >> 6;
    int t0 = blockIdx.x * 64, c0 = blockIdx.y * 64;
#pragma unroll
    for (int r = 0; r < 64; r += 4)
        tile[ty + r][tx] = src[(size_t)(c0 + ty + r) * TT + t0 + tx];
    __syncthreads();
#pragma unroll
    for (int r = 0; r < 64; r += 4)
        dst[(size_t)(t0 + ty + r) * CC + c0 + tx] = f2bf(tile[tx][ty + r]);
}

// ------- 128x128x64 bf16 MFMA GEMM core, double-buffered + prefetch (T3-min) --
// Wm: [512][512] bf16 (o,k) row-major. Sm: [4096][512] bf16 (t,k) row-major.
// TMAJOR=0: Df[o][t] fp32 = W*S^T + bias.
// TMAJOR=1: Db[t][o] bf16 = (W*S^T)^T + bias (swapped MFMA operands).
// Schedule per K-tile: issue STAGE(next) -> ds_read+MFMA(cur) -> one barrier
// (drains vmcnt+lgkm: prefetch visible, cur reads retired before overwrite).
template <int TMAJOR>
__device__ __forceinline__ void gemm128(const short* __restrict__ Wm,
                                        const short* __restrict__ Sm,
                                        const float* __restrict__ bias,
                                        float* __restrict__ Df,
                                        short* __restrict__ Db) {
    __shared__ short Al[2][128 * 64] __attribute__((aligned(16)));
    __shared__ short Bl[2][128 * 64] __attribute__((aligned(16)));
    const int tid = threadIdx.x;
    const int lane = tid & 63;
    const int wid = tid >> 6;
    const int o0 = blockIdx.y * 128;
    const int t0 = blockIdx.x * 128;
    const int wm = (wid >> 1) * 64;
    const int wn = (wid & 1) * 64;

    f32x4 acc[4][4];
#pragma unroll
    for (int i = 0; i < 4; i++)
#pragma unroll
        for (int j = 0; j < 4; j++) acc[i][j] = (f32x4){0.f, 0.f, 0.f, 0.f};

    const int cbase = (wid * 4) << 6;  // chunk base for this wave (64 chunks/call)

#define STAGE_AB(BUF, K0)                                                     \
    {                                                                         \
        _Pragma("unroll") for (int j = 0; j < 4; ++j) {                       \
            int c = cbase + (j << 6) + lane; /* 16B chunk index 0..1023 */    \
            int m = c >> 3, kc = c & 7;                                       \
            int kcs = kc ^ (m & 7); /* pre-swizzled source chunk */           \
            gld_lds16(Wm + (size_t)(o0 + m) * CC + (K0) + kcs * 8,            \
                      &Al[BUF][(cbase + (j << 6)) << 3]);                     \
            gld_lds16(Sm + (size_t)(t0 + m) * CC + (K0) + kcs * 8,            \
                      &Bl[BUF][(cbase + (j << 6)) << 3]);                     \
        }                                                                     \
    }

    STAGE_AB(0, 0);
    __syncthreads();  // prologue tile visible

#pragma unroll
    for (int kt = 0; kt < 8; ++kt) {
        const int buf = kt & 1;
        if (kt < 7) STAGE_AB(buf ^ 1, (kt + 1) * 64);  // prefetch next K-tile

#pragma unroll
        for (int kk = 0; kk < 2; ++kk) {
            const int kb = kk * 32 + (lane >> 4) * 8;
            s16x8 af[4], bfr[4];
#pragma unroll
            for (int i = 0; i < 4; i++) {
                int m = wm + i * 16 + (lane & 15);
                af[i] = *(const s16x8*)&Al[buf][(m * 64 + kb) ^ ((m & 7) << 3)];
                int n = wn + i * 16 + (lane & 15);
                bfr[i] = *(const s16x8*)&Bl[buf][(n * 64 + kb) ^ ((n & 7) << 3)];
            }
#pragma unroll
            for (int mi = 0; mi < 4; mi++)
#pragma unroll
                for (int ni = 0; ni < 4; ni++) {
                    if (TMAJOR)   // rows = t (bfr tile), cols = o (af tile)
                        acc[mi][ni] = __builtin_amdgcn_mfma_f32_16x16x32_bf16(
                            bfr[mi], af[ni], acc[mi][ni], 0, 0, 0);
                    else
                        acc[mi][ni] = __builtin_amdgcn_mfma_f32_16x16x32_bf16(
                            af[mi], bfr[ni], acc[mi][ni], 0, 0, 0);
                }
        }
        __syncthreads();  // vmcnt(0)+lgkm(0): prefetch landed, cur reads done
    }
#undef STAGE_AB

    const int col = lane & 15;
    const int rg = (lane >> 4) << 2;
    if (TMAJOR) {
#pragma unroll
        for (int ti = 0; ti < 4; ti++) {
            int t = t0 + wn + ti * 16 + rg;
#pragma unroll
            for (int oi = 0; oi < 4; oi++) {
                int o = o0 + wm + oi * 16 + col;
                float bv = bias[o];
                f32x4 a = acc[ti][oi];
#pragma unroll
                for (int r = 0; r < 4; r++)
                    Db[(size_t)(t + r) * CC + o] = f2bf(a[r] + bv);
            }
        }
    } else {
#pragma unroll
        for (int mi = 0; mi < 4; mi++) {
            int o = o0 + wm + mi * 16 + rg;
#pragma unroll
            for (int ni = 0; ni < 4; ni++) {
                int t = t0 + wn + ni * 16 + col;
                f32x4 a = acc[mi][ni];
#pragma unroll
                for (int r = 0; r < 4; r++)
                    Df[(size_t)(o + r) * TT + t] = a[r] + bias[o + r];
            }
        }
    }
}

// QKV: writes bf16 [which][b][t][C]
__global__ __launch_bounds__(256, 2) void gemm_qkv_k(
    const short* __restrict__ Wb, const short* __restrict__ xT,
    const short* __restrict__ condT, const float* __restrict__ bq,
    const float* __restrict__ bk, const float* __restrict__ bv,
    short* __restrict__ qkvT) {
    int z = blockIdx.z, which = z >> 2, b = z & 3;
    const short* Wm = Wb + (size_t)which * CC * CC;
    const short* Sm = (which == 0 ? xT : condT) + (size_t)b * TT * CC;
    const float* bias = which == 0 ? bq : (which == 1 ? bk : bv);
    short* Db = qkvT + ((size_t)which * NB + b) * TT * CC;
    gemm128<1>(Wm, Sm, bias, nullptr, Db);
}

__global__ __launch_bounds__(256, 2) void gemm_o_k(const short* __restrict__ Wb,
                                                   const short* __restrict__ outT,
                                                   const float* __restrict__ bo,
                                                   float* __restrict__ out) {
    int b = blockIdx.z;
    gemm128<0>(Wb + 3 * (size_t)CC * CC, outT + (size_t)b * TT * CC, bo,
               out + (size_t)b * CC * TT, nullptr);
}

// ---------------- windowed attention v5: two-buffer, gld_lds, 4-acc ILP -------
// qkvT: bf16 [3][B][T][C]; out: bf16 [B][T][C].
// Block = 64 threads = one (b, h, 64-t tile). K and V bands (80 rows x 8
// 16B-chunks each, slot XOR swizzle c^(row&7)) staged in parallel via
// global_load_lds with clamped source rows; OOB handled by masking logits
// and p-weights in registers (zero-pad semantics).
__global__ __launch_bounds__(64, 4) void attn5_k(const short* __restrict__ qkvT,
                                                 short* __restrict__ outT) {
    __shared__ unsigned kl[640 * 4] __attribute__((aligned(16)));
    __shared__ unsigned vl[640 * 4] __attribute__((aligned(16)));
    const int lane = threadIdx.x;
    const int t0 = blockIdx.x * 64;
    const int h = blockIdx.y, b = blockIdx.z;
    const size_t BTC = (size_t)NB * TT * CC;
    const short* qg = qkvT + (size_t)b * TT * CC + h * HD;
    const short* kg = qg + BTC;
    const short* vg = qg + 2 * BTC;

    // ---- stage K and V bands together (20 loads in flight) ----
#pragma unroll
    for (int it = 0; it < 10; ++it) {
        int idx = it * 64 + lane;          // chunk index 0..639
        int row = idx >> 3, s = idx & 7;
        int c = s ^ (row & 7);             // LDS slot s holds global chunk c
        int t = t0 - 8 + row;
        t = t < 0 ? 0 : (t > TT - 1 ? TT - 1 : t);
        const size_t off = (size_t)t * CC + c * 8;
        gld_lds16(kg + off, &kl[it * 256]);
        gld_lds16(vg + off, &vl[it * 256]);
    }

    // own Q row -> packed bf16 dwords (no conversion)
    u32x4 qv[8];
    {
        const u32x4* qr = (const u32x4*)(qg + (size_t)(t0 + lane) * CC);
#pragma unroll
        for (int c = 0; c < 8; ++c) qv[c] = qr[c];
    }

    __syncthreads();  // drains vmcnt(0)+lgkmcnt: K,V staged, Q loaded

    // ---- QK^T, 4-way split accumulators (chain depth 8) ----
    float dots[16];
#pragma unroll
    for (int w = 0; w < 16; ++w) {
        const int row = lane + w;          // LDS row (key t = t0-8+row)
        float a0 = 0.f, a1 = 0.f, a2 = 0.f, a3 = 0.f;
#pragma unroll
        for (int c = 0; c < 8; ++c) {
            u32x4 kc = *(const u32x4*)&kl[(row * 8 + (c ^ (row & 7))) * 4];
            a0 = dot2bf(qv[c][0], kc[0], a0);
            a1 = dot2bf(qv[c][1], kc[1], a1);
            a2 = dot2bf(qv[c][2], kc[2], a2);
            a3 = dot2bf(qv[c][3], kc[3], a3);
        }
        int s = t0 - 8 + row;
        // zero-pad semantics: OOB key row -> logit exactly 0
        dots[w] = ((unsigned)s < (unsigned)TT) ? ((a0 + a1) + (a2 + a3)) * 0.125f
                                               : 0.f;
    }

    // ---- softmax + pack p (bf16 pairs), masked for OOB ----
    unsigned pp[8];
    {
        float mx = dots[0];
#pragma unroll
        for (int w = 1; w < 16; ++w) mx = fmaxf(mx, dots[w]);
        float e[16], sum = 0.f;
#pragma unroll
        for (int w = 0; w < 16; ++w) {
            e[w] = __expf(dots[w] - mx);
            sum += e[w];
        }
        const float inv = 1.f / sum;
        const int sb = t0 - 8 + lane;
#pragma unroll
        for (int i = 0; i < 8; ++i) {
            float p0 = ((unsigned)(sb + 2 * i) < (unsigned)TT) ? e[2 * i] * inv : 0.f;
            float p1 = ((unsigned)(sb + 2 * i + 1) < (unsigned)TT) ? e[2 * i + 1] * inv : 0.f;
            pp[i] = (unsigned)(unsigned short)f2bf(p0) |
                    ((unsigned)(unsigned short)f2bf(p1) << 16);
        }
    }

    // ---- PV in two d-halves (32 fp32 accumulators live at a time) ----
    short* ob = outT + ((size_t)b * TT + t0 + lane) * CC + h * HD;
#pragma unroll
    for (int half = 0; half < 2; ++half) {
        float of[32];
#pragma unroll
        for (int j = 0; j < 32; ++j) of[j] = 0.f;
#pragma unroll
        for (int i = 0; i < 8; ++i) {
            const int r0 = lane + 2 * i, r1 = r0 + 1;
#pragma unroll
            for (int cl = 0; cl < 4; ++cl) {
                const int c = half * 4 + cl;
                u32x4 va = *(const u32x4*)&vl[(r0 * 8 + (c ^ (r0 & 7))) * 4];
                u32x4 vb = *(const u32x4*)&vl[(r1 * 8 + (c ^ (r1 & 7))) * 4];
#pragma unroll
                for (int d = 0; d < 4; ++d) {
                    unsigned lo = __builtin_amdgcn_perm(vb[d], va[d], 0x05040100u);
                    unsigned hi = __builtin_amdgcn_perm(vb[d], va[d], 0x07060302u);
                    of[cl * 8 + 2 * d]     = dot2bf(pp[i], lo, of[cl * 8 + 2 * d]);
                    of[cl * 8 + 2 * d + 1] = dot2bf(pp[i], hi, of[cl * 8 + 2 * d + 1]);
                }
            }
        }
#pragma unroll
        for (int cl = 0; cl < 4; ++cl) {
            s16x8 pk;
#pragma unroll
            for (int j = 0; j < 8; ++j) pk[j] = f2bf(of[cl * 8 + j]);
            *(s16x8*)&ob[half * 32 + cl * 8] = pk;
        }
    }
}

extern "C" void kernel_launch(void* const* d_in, const int* in_sizes, int n_in,
                              void* d_out, int out_size, void* d_ws, size_t ws_size,
                              hipStream_t stream) {
    const float* x    = (const float*)d_in[0];
    const float* cond = (const float*)d_in[1];
    const float* Wq   = (const float*)d_in[2];
    const float* bq   = (const float*)d_in[3];
    const float* Wk   = (const float*)d_in[4];
    const float* bk   = (const float*)d_in[5];
    const float* Wv   = (const float*)d_in[6];
    const float* bv   = (const float*)d_in[7];
    const float* Wo   = (const float*)d_in[8];
    const float* bo   = (const float*)d_in[9];

    char* ws = (char*)d_ws;
    // layout: Wb(2MB) | xT(16MB) | condT(16MB) | qkvT bf16 (48MB)
    short* Wb    = (short*)ws;
    short* xT    = (short*)(ws + (2u << 20));
    short* condT = (short*)(ws + (18u << 20));
    short* qkvT  = (short*)(ws + (34u << 20));
    short* outT  = xT;  // xT dead after Q GEMM; reuse for attention output^T

    cvt_w_k<<<4096, 256, 0, stream>>>(Wq, Wk, Wv, Wo, Wb);
    trans_k<<<dim3(TT / 64, CC / 64, 8), 256, 0, stream>>>(x, cond, xT, condT);
    gemm_qkv_k<<<dim3(TT / 128, CC / 128, 12), 256, 0, stream>>>(Wb, xT, condT, bq, bk, bv, qkvT);
    attn5_k<<<dim3(TT / 64, NH, NB), 64, 0, stream>>>(qkvT, outT);
    gemm_o_k<<<dim3(TT / 128, CC / 128, 4), 256, 0, stream>>>(Wb, outT, bo, (float*)d_out);
}

// Round 9
// 93.765 us; speedup vs baseline: 1.5101x; 1.0280x over previous
//
#include <hip/hip_runtime.h>

#define CC 512
#define TT 4096
#define NB 4
#define NH 8
#define HD 64

typedef __attribute__((ext_vector_type(8))) short s16x8;
typedef __attribute__((ext_vector_type(4))) float f32x4;
typedef __attribute__((ext_vector_type(4))) unsigned int u32x4;

#if defined(__has_builtin)
#  if __has_builtin(__builtin_amdgcn_fdot2_f32_bf16)
#    define HAS_BF16_DOT2 1
#  else
#    define HAS_BF16_DOT2 0
#  endif
#else
#  define HAS_BF16_DOT2 0
#endif

// float -> bf16 bits, round-to-nearest-even
__device__ __forceinline__ short f2bf(float f) {
    unsigned u = __float_as_uint(f);
    unsigned r = (u + 0x7fffu + ((u >> 16) & 1u)) >> 16;
    return (short)r;
}
__device__ __forceinline__ float bf2f(short s) {
    return __uint_as_float(((unsigned)(unsigned short)s) << 16);
}

#if HAS_BF16_DOT2
typedef __attribute__((ext_vector_type(2))) __bf16 bf16x2;
__device__ __forceinline__ float dot2bf(unsigned a, unsigned b, float c) {
    return __builtin_amdgcn_fdot2_f32_bf16(__builtin_bit_cast(bf16x2, a),
                                           __builtin_bit_cast(bf16x2, b), c, false);
}
#else
__device__ __forceinline__ float dot2bf(unsigned a, unsigned b, float c) {
    float r = fmaf(bf2f((short)(a & 0xffffu)), bf2f((short)(b & 0xffffu)), c);
    return fmaf(bf2f((short)(a >> 16)), bf2f((short)(b >> 16)), r);
}
#endif

__device__ __forceinline__ void gld_lds16(const void* g, void* s) {
    __builtin_amdgcn_global_load_lds(
        (const __attribute__((address_space(1))) unsigned int*)g,
        (__attribute__((address_space(3))) unsigned int*)s, 16, 0, 0);
}

// ---------------- weight fp32 -> bf16 (4 matrices concatenated) ----------------
__global__ __launch_bounds__(256) void cvt_w_k(const float* __restrict__ w0,
                                               const float* __restrict__ w1,
                                               const float* __restrict__ w2,
                                               const float* __restrict__ w3,
                                               short* __restrict__ dst) {
    int i = blockIdx.x * 256 + threadIdx.x;  // 4*262144 total
    const float* s = (i < 262144) ? w0 : (i < 524288) ? w1 : (i < 786432) ? w2 : w3;
    dst[i] = f2bf(s[i & 262143]);
}

// ---------- transpose+convert: fp32 (B,C,T) -> bf16 (B,T,C), x and cond -------
__global__ __launch_bounds__(256) void trans_k(const float* __restrict__ x,
                                               const float* __restrict__ cond,
                                               short* __restrict__ xT,
                                               short* __restrict__ condT) {
    __shared__ float tile[64][65];
    int z = blockIdx.z;          // 0..7
    int b = z & 3;
    const float* src = (z < 4 ? x : cond) + (size_t)b * CC * TT;
    short* dst = (z < 4 ? xT : condT) + (size_t)b * TT * CC;
    int tx = threadIdx.x & 63, ty = threadIdx.x >> 6;
    int t0 = blockIdx.x * 64, c0 = blockIdx.y * 64;
#pragma unroll
    for (int r = 0; r < 64; r += 4)
        tile[ty + r][tx] = src[(size_t)(c0 + ty + r) * TT + t0 + tx];
    __syncthreads();
#pragma unroll
    for (int r = 0; r < 64; r += 4)
        dst[(size_t)(t0 + ty + r) * CC + c0 + tx] = f2bf(tile[tx][ty + r]);
}

// ---------------- 128x128x64 bf16 MFMA GEMM core (r5-proven) ----------------
// Wm: [512][512] bf16 (o,k) row-major. Sm: [4096][512] bf16 (t,k) row-major.
// TMAJOR=0: Df[o][t] fp32 = W*S^T + bias.
// TMAJOR=1: Db[t][o] bf16 = (W*S^T)^T + bias (swapped MFMA operands).
template <int TMAJOR>
__device__ __forceinline__ void gemm128(const short* __restrict__ Wm,
                                        const short* __restrict__ Sm,
                                        const float* __restrict__ bias,
                                        float* __restrict__ Df,
                                        short* __restrict__ Db) {
    __shared__ short Al[128 * 64] __attribute__((aligned(16)));
    __shared__ short Bl[128 * 64] __attribute__((aligned(16)));
    const int tid = threadIdx.x;
    const int lane = tid & 63;
    const int wid = tid >> 6;
    const int o0 = blockIdx.y * 128;
    const int t0 = blockIdx.x * 128;
    const int wm = (wid >> 1) * 64;
    const int wn = (wid & 1) * 64;

    f32x4 acc[4][4];
#pragma unroll
    for (int i = 0; i < 4; i++)
#pragma unroll
        for (int j = 0; j < 4; j++) acc[i][j] = (f32x4){0.f, 0.f, 0.f, 0.f};

    const int cbase = (wid * 4) << 6;  // chunk base for this wave (64 chunks/call)

    for (int kt = 0; kt < 8; ++kt) {
        const int k0 = kt * 64;
        __syncthreads();  // previous tile's reads complete
#pragma unroll
        for (int j = 0; j < 4; ++j) {
            int c = cbase + (j << 6) + lane;   // 16B chunk index 0..1023
            int m = c >> 3, kc = c & 7;
            int kcs = kc ^ (m & 7);            // pre-swizzled source chunk
            gld_lds16(Wm + (size_t)(o0 + m) * CC + k0 + kcs * 8,
                      &Al[(cbase + (j << 6)) << 3]);
            gld_lds16(Sm + (size_t)(t0 + m) * CC + k0 + kcs * 8,
                      &Bl[(cbase + (j << 6)) << 3]);
        }
        __syncthreads();  // drains vmcnt(0): staged data visible
#pragma unroll
        for (int kk = 0; kk < 2; ++kk) {
            const int kb = kk * 32 + (lane >> 4) * 8;
            s16x8 af[4], bfr[4];
#pragma unroll
            for (int i = 0; i < 4; i++) {
                int m = wm + i * 16 + (lane & 15);
                af[i] = *(const s16x8*)&Al[(m * 64 + kb) ^ ((m & 7) << 3)];
                int n = wn + i * 16 + (lane & 15);
                bfr[i] = *(const s16x8*)&Bl[(n * 64 + kb) ^ ((n & 7) << 3)];
            }
#pragma unroll
            for (int mi = 0; mi < 4; mi++)
#pragma unroll
                for (int ni = 0; ni < 4; ni++) {
                    if (TMAJOR)   // rows = t (bfr tile), cols = o (af tile)
                        acc[mi][ni] = __builtin_amdgcn_mfma_f32_16x16x32_bf16(
                            bfr[mi], af[ni], acc[mi][ni], 0, 0, 0);
                    else
                        acc[mi][ni] = __builtin_amdgcn_mfma_f32_16x16x32_bf16(
                            af[mi], bfr[ni], acc[mi][ni], 0, 0, 0);
                }
        }
    }

    const int col = lane & 15;
    const int rg = (lane >> 4) << 2;
    if (TMAJOR) {
#pragma unroll
        for (int ti = 0; ti < 4; ti++) {
            int t = t0 + wn + ti * 16 + rg;
#pragma unroll
            for (int oi = 0; oi < 4; oi++) {
                int o = o0 + wm + oi * 16 + col;
                float bv = bias[o];
                f32x4 a = acc[ti][oi];
#pragma unroll
                for (int r = 0; r < 4; r++)
                    Db[(size_t)(t + r) * CC + o] = f2bf(a[r] + bv);
            }
        }
    } else {
#pragma unroll
        for (int mi = 0; mi < 4; mi++) {
            int o = o0 + wm + mi * 16 + rg;
#pragma unroll
            for (int ni = 0; ni < 4; ni++) {
                int t = t0 + wn + ni * 16 + col;
                f32x4 a = acc[mi][ni];
#pragma unroll
                for (int r = 0; r < 4; r++)
                    Df[(size_t)(o + r) * TT + t] = a[r] + bias[o + r];
            }
        }
    }
}

// QKV: writes bf16 [which][b][t][C]
__global__ __launch_bounds__(256, 2) void gemm_qkv_k(
    const short* __restrict__ Wb, const short* __restrict__ xT,
    const short* __restrict__ condT, const float* __restrict__ bq,
    const float* __restrict__ bk, const float* __restrict__ bv,
    short* __restrict__ qkvT) {
    int z = blockIdx.z, which = z >> 2, b = z & 3;
    const short* Wm = Wb + (size_t)which * CC * CC;
    const short* Sm = (which == 0 ? xT : condT) + (size_t)b * TT * CC;
    const float* bias = which == 0 ? bq : (which == 1 ? bk : bv);
    short* Db = qkvT + ((size_t)which * NB + b) * TT * CC;
    gemm128<1>(Wm, Sm, bias, nullptr, Db);
}

__global__ __launch_bounds__(256, 2) void gemm_o_k(const short* __restrict__ Wb,
                                                   const short* __restrict__ outT,
                                                   const float* __restrict__ bo,
                                                   float* __restrict__ out) {
    int b = blockIdx.z;
    gemm128<0>(Wb + 3 * (size_t)CC * CC, outT + (size_t)b * TT * CC, bo,
               out + (size_t)b * CC * TT, nullptr);
}

// -------- windowed attention v7: 32-t waves, 2 lanes/t (d-split), 12KB LDS ----
// qkvT: bf16 [3][B][T][C]; out: bf16 [B][T][C].
// Block = 64 threads = one (b, h, 32-t tile). lane&31 -> t offset; lane>>5 ->
// d-half (chunks dh*4..dh*4+3). Band rows [t0-8, t0+39] (48 rows x 8 chunks,
// slot XOR swizzle c^(row&7)); each lane reads only its 4 d-chunks. QK partial
// dots combined across the d-halves with one shfl_xor(32). Zero-pad semantics
// via clamped staging + logit/p masks.
__global__ __launch_bounds__(64, 4) void attn7_k(const short* __restrict__ qkvT,
                                                 short* __restrict__ outT) {
    __shared__ unsigned kl[384 * 4] __attribute__((aligned(16)));
    __shared__ unsigned vl[384 * 4] __attribute__((aligned(16)));
    const int lane = threadIdx.x;
    const int tl = lane & 31;          // t within tile
    const int dh = lane >> 5;          // d-half: chunk base dh*4
    const int t0 = blockIdx.x * 32;
    const int h = blockIdx.y, b = blockIdx.z;
    const size_t BTC = (size_t)NB * TT * CC;
    const short* qg = qkvT + (size_t)b * TT * CC + h * HD;
    const short* kg = qg + BTC;
    const short* vg = qg + 2 * BTC;

    // ---- stage K and V bands (48 rows x 8 chunks each; 6 chunks/lane each) ----
#pragma unroll
    for (int it = 0; it < 6; ++it) {
        int idx = it * 64 + lane;          // chunk index 0..383
        int row = idx >> 3, s = idx & 7;
        int c = s ^ (row & 7);             // LDS slot s holds global chunk c
        int t = t0 - 8 + row;
        t = t < 0 ? 0 : (t > TT - 1 ? TT - 1 : t);
        const size_t off = (size_t)t * CC + c * 8;
        gld_lds16(kg + off, &kl[it * 256]);
        gld_lds16(vg + off, &vl[it * 256]);
    }

    // own Q half-row -> packed bf16 dwords (chunks dh*4 .. dh*4+3)
    u32x4 qv[4];
    {
        const u32x4* qr = (const u32x4*)(qg + (size_t)(t0 + tl) * CC + dh * 32);
#pragma unroll
        for (int c = 0; c < 4; ++c) qv[c] = qr[c];
    }

    __syncthreads();  // drains vmcnt+lgkm: K,V staged, Q loaded

    // ---- QK^T over 4 chunks (half the dot); combine halves via shfl ----
    float dots[16];
#pragma unroll
    for (int w = 0; w < 16; ++w) {
        const int row = tl + w;            // LDS row (key t = t0-8+row)
        float a0 = 0.f, a1 = 0.f, a2 = 0.f, a3 = 0.f;
#pragma unroll
        for (int cc = 0; cc < 4; ++cc) {
            const int c = dh * 4 + cc;
            u32x4 kc = *(const u32x4*)&kl[(row * 8 + (c ^ (row & 7))) * 4];
            a0 = dot2bf(qv[cc][0], kc[0], a0);
            a1 = dot2bf(qv[cc][1], kc[1], a1);
            a2 = dot2bf(qv[cc][2], kc[2], a2);
            a3 = dot2bf(qv[cc][3], kc[3], a3);
        }
        dots[w] = (a0 + a1) + (a2 + a3);
    }
#pragma unroll
    for (int w = 0; w < 16; ++w) {
        float full = dots[w] + __shfl_xor(dots[w], 32);
        int s = t0 - 8 + tl + w;
        // zero-pad semantics: OOB key row -> logit exactly 0
        dots[w] = ((unsigned)s < (unsigned)TT) ? full * 0.125f : 0.f;
    }

    // ---- softmax + pack p (bf16 pairs), masked for OOB ----
    unsigned pp[8];
    {
        float mx = dots[0];
#pragma unroll
        for (int w = 1; w < 16; ++w) mx = fmaxf(mx, dots[w]);
        float e[16], sum = 0.f;
#pragma unroll
        for (int w = 0; w < 16; ++w) {
            e[w] = __expf(dots[w] - mx);
            sum += e[w];
        }
        const float inv = 1.f / sum;
        const int sb = t0 - 8 + tl;
#pragma unroll
        for (int i = 0; i < 8; ++i) {
            float p0 = ((unsigned)(sb + 2 * i) < (unsigned)TT) ? e[2 * i] * inv : 0.f;
            float p1 = ((unsigned)(sb + 2 * i + 1) < (unsigned)TT) ? e[2 * i + 1] * inv : 0.f;
            pp[i] = (unsigned)(unsigned short)f2bf(p0) |
                    ((unsigned)(unsigned short)f2bf(p1) << 16);
        }
    }

    // ---- PV over this lane's 4 d-chunks (32 fp32 accumulators) ----
    float of[32];
#pragma unroll
    for (int j = 0; j < 32; ++j) of[j] = 0.f;
#pragma unroll
    for (int i = 0; i < 8; ++i) {
        const int r0 = tl + 2 * i, r1 = r0 + 1;
#pragma unroll
        for (int cc = 0; cc < 4; ++cc) {
            const int c = dh * 4 + cc;
            u32x4 va = *(const u32x4*)&vl[(r0 * 8 + (c ^ (r0 & 7))) * 4];
            u32x4 vb = *(const u32x4*)&vl[(r1 * 8 + (c ^ (r1 & 7))) * 4];
#pragma unroll
            for (int d = 0; d < 4; ++d) {
                unsigned lo = __builtin_amdgcn_perm(vb[d], va[d], 0x05040100u);
                unsigned hi = __builtin_amdgcn_perm(vb[d], va[d], 0x07060302u);
                of[cc * 8 + 2 * d]     = dot2bf(pp[i], lo, of[cc * 8 + 2 * d]);
                of[cc * 8 + 2 * d + 1] = dot2bf(pp[i], hi, of[cc * 8 + 2 * d + 1]);
            }
        }
    }
    short* ob = outT + ((size_t)b * TT + t0 + tl) * CC + h * HD + dh * 32;
#pragma unroll
    for (int cc = 0; cc < 4; ++cc) {
        s16x8 pk;
#pragma unroll
        for (int j = 0; j < 8; ++j) pk[j] = f2bf(of[cc * 8 + j]);
        *(s16x8*)&ob[cc * 8] = pk;
    }
}

extern "C" void kernel_launch(void* const* d_in, const int* in_sizes, int n_in,
                              void* d_out, int out_size, void* d_ws, size_t ws_size,
                              hipStream_t stream) {
    const float* x    = (const float*)d_in[0];
    const float* cond = (const float*)d_in[1];
    const float* Wq   = (const float*)d_in[2];
    const float* bq   = (const float*)d_in[3];
    const float* Wk   = (const float*)d_in[4];
    const float* bk   = (const float*)d_in[5];
    const float* Wv   = (const float*)d_in[6];
    const float* bv   = (const float*)d_in[7];
    const float* Wo   = (const float*)d_in[8];
    const float* bo   = (const float*)d_in[9];

    char* ws = (char*)d_ws;
    // layout: Wb(2MB) | xT(16MB) | condT(16MB) | qkvT bf16 (48MB)
    short* Wb    = (short*)ws;
    short* xT    = (short*)(ws + (2u << 20));
    short* condT = (short*)(ws + (18u << 20));
    short* qkvT  = (short*)(ws + (34u << 20));
    short* outT  = xT;  // xT dead after Q GEMM; reuse for attention output^T

    cvt_w_k<<<4096, 256, 0, stream>>>(Wq, Wk, Wv, Wo, Wb);
    trans_k<<<dim3(TT / 64, CC / 64, 8), 256, 0, stream>>>(x, cond, xT, condT);
    gemm_qkv_k<<<dim3(TT / 128, CC / 128, 12), 256, 0, stream>>>(Wb, xT, condT, bq, bk, bv, qkvT);
    attn7_k<<<dim3(TT / 32, NH, NB), 64, 0, stream>>>(qkvT, outT);
    gemm_o_k<<<dim3(TT / 128, CC / 128, 4), 256, 0, stream>>>(Wb, outT, bo, (float*)d_out);
}